// Round 3
// baseline (87.816 us; speedup 1.0000x reference)
//
#include <hip/hip_runtime.h>
#include <math.h>

// Problem constants
#define NPIX   (512 * 3072)     // 1,572,864 pixels (= flat x length)
#define NCLS   10
#define NLAYER 3
#define PI_4   0.78539816339744830962f

// ---------------------------------------------------------------------------
// Fully fused kernel.
//
// |s0(x)|^2 of the 3-layer re-uploading circuit is exactly band-limited to
// the 3rd harmonic of x, so out[p][c] = a0 + sum_{m=1..3} am cos(mx) + bm
// sin(mx): 7 coefficients per class, recovered exactly by an 8-point DFT of
// the circuit sampled at x_k = k*pi/4.
//
// Per block:
//   phase 1: threads 0..79 evaluate the circuit (precise sincosf) at the
//            8 sample angles for their class -> y[80] in LDS
//   phase 2: threads 0..69 do the 8-point DFT -> coef[70] in LDS
//   phase 3: every thread bulk-loads coef (18x ds_read_b128 broadcast),
//            computes 2 pixels x 10 classes with __sincosf + double/triple
//            angle recurrences, stages 20 floats to LDS, then the block
//            streams the 20 KB tile out as contiguous wave-wide float4
//            stores (1 KB per store instruction).
//
// Redundant per-block coefficient computation (~400 cycles) removes the
// separate coef kernel + its graph-node serialization entirely.
// ---------------------------------------------------------------------------
__global__ __launch_bounds__(256) void fused_kernel(const float* __restrict__ x,
                                                    const float* __restrict__ params,
                                                    float* __restrict__ out) {
    __shared__ __align__(16) float y[80];       // y[c*8 + k]
    __shared__ __align__(16) float coef[72];    // [class][7], padded to 72
    __shared__ __align__(16) float tile[5120];  // 20 KB output staging

    const int t = threadIdx.x;
    const int g = blockIdx.x * 256 + t;         // pixel-pair index

    // coalesced input load, issued early
    const float2 xv = ((const float2* __restrict__)x)[g];

    // ---- phase 1: circuit eval at 8 sample angles per class ----
    if (t < NCLS * 8) {
        const int c = t >> 3;
        const int k = t & 7;
        const float xs = (float)k * PI_4;

        float s0r = 1.f, s0i = 0.f, s1r = 0.f, s1i = 0.f;

        #pragma unroll
        for (int l = 0; l < NLAYER; ++l) {
            // Ry(x)
            {
                float sh, ch;
                sincosf(0.5f * xs, &sh, &ch);
                float n0r = ch * s0r - sh * s1r;
                float n0i = ch * s0i - sh * s1i;
                float n1r = sh * s0r + ch * s1r;
                float n1i = sh * s0i + ch * s1i;
                s0r = n0r; s0i = n0i; s1r = n1r; s1i = n1i;
            }
            // Rz(g0): s0 *= e^{-i th}, s1 *= e^{+i th}
            {
                float th = 0.5f * params[(c * NLAYER + l) * 3 + 0];
                float st, ct;
                sincosf(th, &st, &ct);
                float n0r = s0r * ct + s0i * st;
                float n0i = s0i * ct - s0r * st;
                float n1r = s1r * ct - s1i * st;
                float n1i = s1i * ct + s1r * st;
                s0r = n0r; s0i = n0i; s1r = n1r; s1i = n1i;
            }
            // Ry(g1)
            {
                float th = 0.5f * params[(c * NLAYER + l) * 3 + 1];
                float sh, ch;
                sincosf(th, &sh, &ch);
                float n0r = ch * s0r - sh * s1r;
                float n0i = ch * s0i - sh * s1i;
                float n1r = sh * s0r + ch * s1r;
                float n1i = sh * s0i + ch * s1i;
                s0r = n0r; s0i = n0i; s1r = n1r; s1i = n1i;
            }
            // Rz(g2)
            {
                float th = 0.5f * params[(c * NLAYER + l) * 3 + 2];
                float st, ct;
                sincosf(th, &st, &ct);
                float n0r = s0r * ct + s0i * st;
                float n0i = s0i * ct - s0r * st;
                float n1r = s1r * ct - s1i * st;
                float n1i = s1i * ct + s1r * st;
                s0r = n0r; s0i = n0i; s1r = n1r; s1i = n1i;
            }
        }
        y[t] = s0r * s0r + s0i * s0i;           // t == c*8 + k
    }
    __syncthreads();

    // ---- phase 2: 8-point DFT -> 7 coefficients per class ----
    if (t < NCLS * 7) {
        const int c = t / 7;
        const int j = t % 7;
        float acc = 0.f;
        #pragma unroll
        for (int k = 0; k < 8; ++k) {
            const float ang = (float)k * PI_4;
            float w;
            if (j == 0)       w = 0.125f;
            else if (j <= 3)  w = 0.25f * cosf((float)j * ang);
            else              w = 0.25f * sinf((float)(j - 3) * ang);
            acc += y[c * 8 + k] * w;
        }
        coef[c * 7 + j] = acc;
    }
    __syncthreads();

    // ---- phase 3: per-pixel reconstruction ----
    // bulk broadcast load of coefficients (18x ds_read_b128)
    float cf[72];
    #pragma unroll
    for (int i = 0; i < 18; ++i)
        ((float4*)cf)[i] = ((const float4*)coef)[i];

    const float px[2] = {xv.x, xv.y};
    float r[20];
    #pragma unroll
    for (int p = 0; p < 2; ++p) {
        float s1, c1;
        __sincosf(px[p], &s1, &c1);             // x in [0,1): fast HW path OK
        const float c2 = 2.f * c1 * c1 - 1.f;
        const float s2 = 2.f * s1 * c1;
        const float c3 = c1 * c2 - s1 * s2;
        const float s3 = s1 * c2 + c1 * s2;
        #pragma unroll
        for (int c = 0; c < NCLS; ++c) {
            const float* f = &cf[c * 7];
            r[p * 10 + c] = f[0] + f[1] * c1 + f[2] * c2 + f[3] * c3
                                 + f[4] * s1 + f[5] * s2 + f[6] * s3;
        }
    }

    // stage to LDS: 5x ds_write_b128 at 80 B lane stride (<=2-way alias, free)
    float4* wb = (float4*)&tile[t * 20];
    #pragma unroll
    for (int i = 0; i < 5; ++i) wb[i] = ((const float4*)r)[i];

    __syncthreads();

    // stream out: 5 rounds of contiguous wave-wide float4 stores
    float4* o4 = (float4*)out + (size_t)blockIdx.x * 1280;   // 5120 floats/block
    const float4* l4 = (const float4*)tile;
    #pragma unroll
    for (int i = 0; i < 5; ++i) o4[i * 256 + t] = l4[i * 256 + t];
}

extern "C" void kernel_launch(void* const* d_in, const int* in_sizes, int n_in,
                              void* d_out, int out_size, void* d_ws, size_t ws_size,
                              hipStream_t stream) {
    const float* x      = (const float*)d_in[0];   // [512*3*32*32] fp32
    const float* params = (const float*)d_in[1];   // [10*3*3] fp32
    float* out          = (float*)d_out;           // [512*3072*10] fp32
    (void)d_ws; (void)ws_size;

    const int pairs  = NPIX / 2;                   // 786,432 pixel pairs
    const int blocks = pairs / 256;                // 3,072 (exact)
    fused_kernel<<<blocks, 256, 0, stream>>>(x, params, out);
}

// Round 5
// 82.494 us; speedup vs baseline: 1.0645x; 1.0645x over previous
//
#include <hip/hip_runtime.h>
#include <math.h>

// Problem constants
#define NPIX   (512 * 3072)     // 1,572,864 pixels (= flat x length)
#define NCLS   10
#define NLAYER 3

// Native clang vector types (required by __builtin_nontemporal_*)
typedef float v2f __attribute__((ext_vector_type(2)));
typedef float v4f __attribute__((ext_vector_type(4)));

// sin/cos(k*pi/8), k=0..7  (half-angles of the 8 DFT sample points x_k = k*pi/4)
__device__ __constant__ float SHK[8] = {
    0.0f, 0.38268343236f, 0.70710678119f, 0.92387953251f,
    1.0f, 0.92387953251f, 0.70710678119f, 0.38268343236f };
__device__ __constant__ float CHK[8] = {
    1.0f, 0.92387953251f, 0.70710678119f, 0.38268343236f,
    0.0f, -0.38268343236f, -0.70710678119f, -0.92387953251f };
// cos/sin(i*pi/4), i=0..7 (DFT twiddles)
__device__ __constant__ float CT8[8] = {
    1.0f, 0.70710678119f, 0.0f, -0.70710678119f,
    -1.0f, -0.70710678119f, 0.0f, 0.70710678119f };
__device__ __constant__ float ST8[8] = {
    0.0f, 0.70710678119f, 1.0f, 0.70710678119f,
    0.0f, -0.70710678119f, -1.0f, -0.70710678119f };

// ---------------------------------------------------------------------------
// Fully fused kernel.
//
// |s0(x)|^2 of the 3-layer re-uploading circuit is exactly band-limited to
// the 3rd harmonic of x: out[p][c] = a0 + sum_m am cos(mx) + bm sin(mx).
// 7 coefficients/class, recovered exactly by an 8-point DFT of the circuit
// sampled at x_k = k*pi/4.
//
// phase 1: threads 0..79 ((class,k)) run the circuit at sample k — x-rotation
//          sin/cos from tables, 9 param angles via __sincosf  -> y[80] (LDS)
// phase 2: threads 0..69 do the table-weighted 8-pt DFT       -> coef[70]
// phase 3: all threads pull coef through readfirstlane -> SGPRs (frees ~70
//          VGPRs vs R3), compute 2 pixels x 10 classes, stage 20 floats to
//          LDS, stream the 20 KB tile out as contiguous wave-wide
//          nontemporal float4 stores (1 KB/instruction).
// ---------------------------------------------------------------------------
__global__ __launch_bounds__(256) void fused_kernel(const float* __restrict__ x,
                                                    const float* __restrict__ params,
                                                    float* __restrict__ out) {
    __shared__ __align__(16) float y[80];       // y[c*8 + k]
    __shared__ __align__(16) float coef[72];    // [class][7]
    __shared__ __align__(16) float tile[5120];  // 20 KB output staging

    const int t = threadIdx.x;
    const int g = blockIdx.x * 256 + t;         // pixel-pair index

    // coalesced input load, issued early (read-once -> nontemporal)
    const v2f xv = __builtin_nontemporal_load(&((const v2f*)x)[g]);

    // ---- phase 1: circuit eval at the 8 sample angles per class ----
    if (t < NCLS * 8) {
        const int c = t >> 3;
        const int k = t & 7;
        const float shx = SHK[k], chx = CHK[k];   // Ry(x_k) half-angle sin/cos

        float s0r = 1.f, s0i = 0.f, s1r = 0.f, s1i = 0.f;

        #pragma unroll
        for (int l = 0; l < NLAYER; ++l) {
            // Ry(x_k)
            {
                float n0r = chx * s0r - shx * s1r;
                float n0i = chx * s0i - shx * s1i;
                float n1r = shx * s0r + chx * s1r;
                float n1i = shx * s0i + chx * s1i;
                s0r = n0r; s0i = n0i; s1r = n1r; s1i = n1i;
            }
            // Rz(g0): s0 *= e^{-i th}, s1 *= e^{+i th}
            {
                float th = 0.5f * params[(c * NLAYER + l) * 3 + 0];
                float st, ct;
                __sincosf(th, &st, &ct);
                float n0r = s0r * ct + s0i * st;
                float n0i = s0i * ct - s0r * st;
                float n1r = s1r * ct - s1i * st;
                float n1i = s1i * ct + s1r * st;
                s0r = n0r; s0i = n0i; s1r = n1r; s1i = n1i;
            }
            // Ry(g1)
            {
                float th = 0.5f * params[(c * NLAYER + l) * 3 + 1];
                float sh, ch;
                __sincosf(th, &sh, &ch);
                float n0r = ch * s0r - sh * s1r;
                float n0i = ch * s0i - sh * s1i;
                float n1r = sh * s0r + ch * s1r;
                float n1i = sh * s0i + ch * s1i;
                s0r = n0r; s0i = n0i; s1r = n1r; s1i = n1i;
            }
            // Rz(g2)
            {
                float th = 0.5f * params[(c * NLAYER + l) * 3 + 2];
                float st, ct;
                __sincosf(th, &st, &ct);
                float n0r = s0r * ct + s0i * st;
                float n0i = s0i * ct - s0r * st;
                float n1r = s1r * ct - s1i * st;
                float n1i = s1i * ct + s1r * st;
                s0r = n0r; s0i = n0i; s1r = n1r; s1i = n1i;
            }
        }
        y[t] = s0r * s0r + s0i * s0i;           // t == c*8 + k
    }
    __syncthreads();

    // ---- phase 2: table-weighted 8-point DFT -> 7 coefficients/class ----
    if (t < NCLS * 7) {
        const int c = t / 7;
        const int j = t % 7;
        float acc = 0.f;
        #pragma unroll
        for (int k = 0; k < 8; ++k) {
            float w;
            if (j == 0)       w = 0.125f;
            else if (j <= 3)  w = 0.25f * CT8[(j * k) & 7];
            else              w = 0.25f * ST8[((j - 3) * k) & 7];
            acc += y[c * 8 + k] * w;
        }
        coef[c * 7 + j] = acc;
    }
    __syncthreads();

    // ---- phase 3: per-pixel reconstruction ----
    // block-uniform coefficients -> SGPRs via readfirstlane (broadcast LDS
    // read is conflict-free; frees ~70 VGPRs vs keeping them per-lane)
    float cf[NCLS * 7];
    #pragma unroll
    for (int i = 0; i < NCLS * 7; ++i)
        cf[i] = __int_as_float(
            __builtin_amdgcn_readfirstlane(__float_as_int(coef[i])));

    const float px[2] = {xv.x, xv.y};
    float r[20];
    #pragma unroll
    for (int p = 0; p < 2; ++p) {
        float s1, c1;
        __sincosf(px[p], &s1, &c1);             // x in [0,1): fast path OK
        const float c2 = 2.f * c1 * c1 - 1.f;
        const float s2 = 2.f * s1 * c1;
        const float c3 = c1 * c2 - s1 * s2;
        const float s3 = s1 * c2 + c1 * s2;
        #pragma unroll
        for (int c = 0; c < NCLS; ++c) {
            const float* f = &cf[c * 7];
            r[p * 10 + c] = f[0] + f[1] * c1 + f[2] * c2 + f[3] * c3
                                 + f[4] * s1 + f[5] * s2 + f[6] * s3;
        }
    }

    // stage to LDS: 5x ds_write_b128 at 80 B lane stride (<=2-way alias, free)
    v4f* wb = (v4f*)&tile[t * 20];
    #pragma unroll
    for (int i = 0; i < 5; ++i) wb[i] = ((const v4f*)r)[i];

    __syncthreads();

    // stream out: contiguous wave-wide nontemporal float4 stores
    v4f* o4 = (v4f*)out + (size_t)blockIdx.x * 1280;   // 5120 floats/block
    const v4f* l4 = (const v4f*)tile;
    #pragma unroll
    for (int i = 0; i < 5; ++i)
        __builtin_nontemporal_store(l4[i * 256 + t], &o4[i * 256 + t]);
}

extern "C" void kernel_launch(void* const* d_in, const int* in_sizes, int n_in,
                              void* d_out, int out_size, void* d_ws, size_t ws_size,
                              hipStream_t stream) {
    const float* x      = (const float*)d_in[0];   // [512*3*32*32] fp32
    const float* params = (const float*)d_in[1];   // [10*3*3] fp32
    float* out          = (float*)d_out;           // [512*3072*10] fp32
    (void)d_ws; (void)ws_size;

    const int pairs  = NPIX / 2;                   // 786,432 pixel pairs
    const int blocks = pairs / 256;                // 3,072 (exact)
    fused_kernel<<<blocks, 256, 0, stream>>>(x, params, out);
}